// Round 1
// baseline (49.137 us; speedup 1.0000x reference)
//
#include <hip/hip_runtime.h>

// LayerNormSubspace: out[b,s,h] = xhat[b,s,h] * (alpha[b,s,:] @ W)[h] + (alpha[b,s,:] @ b)[h]
// x: [4,8192,1024] f32, alpha: [4,8192,4] f32, W: [4,1024] f32, b: [4,1024] f32
// 32768 rows of HS=1024. Memory-bound: ~256.5 MiB compulsory traffic -> ~41us ideal.

constexpr int HS = 1024;

__global__ __launch_bounds__(256, 2) void lns_kernel(
    const float* __restrict__ x,
    const float* __restrict__ alpha,
    const float* __restrict__ W,
    const float* __restrict__ Bias,
    float* __restrict__ out,
    int nrows)
{
    const int t = threadIdx.x;
    const int h4 = t * 4;  // this thread's 4-element column within the row

    // Row-invariant: hoist W and b (4 anchors x 4 elems each) into registers once.
    const float4 w0 = *reinterpret_cast<const float4*>(W + 0 * HS + h4);
    const float4 w1 = *reinterpret_cast<const float4*>(W + 1 * HS + h4);
    const float4 w2 = *reinterpret_cast<const float4*>(W + 2 * HS + h4);
    const float4 w3 = *reinterpret_cast<const float4*>(W + 3 * HS + h4);
    const float4 b0 = *reinterpret_cast<const float4*>(Bias + 0 * HS + h4);
    const float4 b1 = *reinterpret_cast<const float4*>(Bias + 1 * HS + h4);
    const float4 b2 = *reinterpret_cast<const float4*>(Bias + 2 * HS + h4);
    const float4 b3 = *reinterpret_cast<const float4*>(Bias + 3 * HS + h4);

    __shared__ float red[8];  // [0..3]=per-wave sum, [4..7]=per-wave sumsq

    for (int row = blockIdx.x; row < nrows; row += gridDim.x) {
        const size_t base = (size_t)row * HS + h4;
        const float4 xv = *reinterpret_cast<const float4*>(x + base);

        float s  = (xv.x + xv.y) + (xv.z + xv.w);
        float ss = fmaf(xv.x, xv.x, fmaf(xv.y, xv.y, fmaf(xv.z, xv.z, xv.w * xv.w)));

        // wave-64 butterfly-ish reduce (shfl_down, width 64)
        #pragma unroll
        for (int off = 32; off > 0; off >>= 1) {
            s  += __shfl_down(s, off, 64);
            ss += __shfl_down(ss, off, 64);
        }
        const int wv = t >> 6;
        if ((t & 63) == 0) { red[wv] = s; red[wv + 4] = ss; }
        __syncthreads();
        s  = (red[0] + red[1]) + (red[2] + red[3]);
        ss = (red[4] + red[5]) + (red[6] + red[7]);
        __syncthreads();  // protect red[] before next iteration overwrites

        const float mean = s * (1.0f / HS);
        const float var  = fmaf(-mean, mean, ss * (1.0f / HS));  // biased variance
        const float rstd = rsqrtf(var + 1e-5f);

        // alpha for this row (uniform across block -> single cache line)
        const float4 av = *reinterpret_cast<const float4*>(alpha + (size_t)row * 4);

        float4 o;
        {
            const float ew = fmaf(av.x, w0.x, fmaf(av.y, w1.x, fmaf(av.z, w2.x, av.w * w3.x)));
            const float eb = fmaf(av.x, b0.x, fmaf(av.y, b1.x, fmaf(av.z, b2.x, av.w * b3.x)));
            o.x = fmaf((xv.x - mean) * rstd, ew, eb);
        }
        {
            const float ew = fmaf(av.x, w0.y, fmaf(av.y, w1.y, fmaf(av.z, w2.y, av.w * w3.y)));
            const float eb = fmaf(av.x, b0.y, fmaf(av.y, b1.y, fmaf(av.z, b2.y, av.w * b3.y)));
            o.y = fmaf((xv.y - mean) * rstd, ew, eb);
        }
        {
            const float ew = fmaf(av.x, w0.z, fmaf(av.y, w1.z, fmaf(av.z, w2.z, av.w * w3.z)));
            const float eb = fmaf(av.x, b0.z, fmaf(av.y, b1.z, fmaf(av.z, b2.z, av.w * b3.z)));
            o.z = fmaf((xv.z - mean) * rstd, ew, eb);
        }
        {
            const float ew = fmaf(av.x, w0.w, fmaf(av.y, w1.w, fmaf(av.z, w2.w, av.w * w3.w)));
            const float eb = fmaf(av.x, b0.w, fmaf(av.y, b1.w, fmaf(av.z, b2.w, av.w * b3.w)));
            o.w = fmaf((xv.w - mean) * rstd, ew, eb);
        }

        *reinterpret_cast<float4*>(out + base) = o;
    }
}

extern "C" void kernel_launch(void* const* d_in, const int* in_sizes, int n_in,
                              void* d_out, int out_size, void* d_ws, size_t ws_size,
                              hipStream_t stream) {
    const float* x     = (const float*)d_in[0];
    const float* alpha = (const float*)d_in[1];
    const float* W     = (const float*)d_in[2];
    const float* Bias  = (const float*)d_in[3];
    float* out = (float*)d_out;

    const int nrows = in_sizes[0] / HS;  // 4*8192 = 32768

    // Persistent grid: 2048 blocks = 256 CUs x 8 blocks/CU, 256 thr = full occupancy.
    const int grid = 2048;
    lns_kernel<<<grid, 256, 0, stream>>>(x, alpha, W, Bias, out, nrows);
}

// Round 3
// 47.290 us; speedup vs baseline: 1.0391x; 1.0391x over previous
//
#include <hip/hip_runtime.h>

// LayerNormSubspace: out[b,s,h] = xhat[b,s,h] * (alpha[b,s,:] @ W)[h] + (alpha[b,s,:] @ b)[h]
// x: [4,8192,1024] f32, alpha: [4,8192,4] f32, W: [4,1024] f32, b: [4,1024] f32
// 32768 rows of HS=1024.
//
// R2 -> R3: fix compile — __builtin_nontemporal_store needs a clang
// ext_vector_type, not HIP_vector_type<float,4>.

constexpr int HS = 1024;

typedef float vfloat4 __attribute__((ext_vector_type(4)));

__device__ __forceinline__ float4 ld4(const float* p) {
    return *reinterpret_cast<const float4*>(p);
}

__device__ __forceinline__ void st4_nt(float* p, float a, float b, float c, float d) {
    vfloat4 v = {a, b, c, d};
    __builtin_nontemporal_store(v, reinterpret_cast<vfloat4*>(p));
}

__global__ __launch_bounds__(256, 8) void lns_kernel(
    const float* __restrict__ x,
    const float* __restrict__ alpha,
    const float* __restrict__ W,
    const float* __restrict__ Bias,
    float* __restrict__ out,
    int nrows)
{
    const int t = threadIdx.x;
    const int h4 = t * 4;  // this thread's 4-element column within the row

    // Row-invariant: hoist W and b (4 anchors x 4 elems each) into registers once. 32 VGPRs.
    const float4 w0 = ld4(W + 0 * HS + h4);
    const float4 w1 = ld4(W + 1 * HS + h4);
    const float4 w2 = ld4(W + 2 * HS + h4);
    const float4 w3 = ld4(W + 3 * HS + h4);
    const float4 b0 = ld4(Bias + 0 * HS + h4);
    const float4 b1 = ld4(Bias + 1 * HS + h4);
    const float4 b2 = ld4(Bias + 2 * HS + h4);
    const float4 b3 = ld4(Bias + 3 * HS + h4);

    // red[parity][0..3]=row0 sum/wave, [4..7]=row0 ss, [8..11]=row1 sum, [12..15]=row1 ss
    __shared__ float red[2][16];

    const int wv = t >> 6;
    int iter = 0;

    for (int row = blockIdx.x * 2; row < nrows; row += gridDim.x * 2, ++iter) {
        const size_t base0 = (size_t)row * HS + h4;
        const size_t base1 = base0 + HS;

        const float4 x0 = ld4(x + base0);
        const float4 x1 = ld4(x + base1);
        const float4 a0 = ld4(alpha + (size_t)row * 4);
        const float4 a1 = ld4(alpha + (size_t)row * 4 + 4);

        float s0  = (x0.x + x0.y) + (x0.z + x0.w);
        float ss0 = fmaf(x0.x, x0.x, fmaf(x0.y, x0.y, fmaf(x0.z, x0.z, x0.w * x0.w)));
        float s1  = (x1.x + x1.y) + (x1.z + x1.w);
        float ss1 = fmaf(x1.x, x1.x, fmaf(x1.y, x1.y, fmaf(x1.z, x1.z, x1.w * x1.w)));

        #pragma unroll
        for (int off = 32; off > 0; off >>= 1) {
            s0  += __shfl_down(s0,  off, 64);
            ss0 += __shfl_down(ss0, off, 64);
            s1  += __shfl_down(s1,  off, 64);
            ss1 += __shfl_down(ss1, off, 64);
        }

        const int p = iter & 1;
        if ((t & 63) == 0) {
            red[p][wv]      = s0;
            red[p][4 + wv]  = ss0;
            red[p][8 + wv]  = s1;
            red[p][12 + wv] = ss1;
        }
        __syncthreads();  // single barrier per 2 rows (parity buffer protects reuse)

        s0  = (red[p][0] + red[p][1]) + (red[p][2] + red[p][3]);
        ss0 = (red[p][4] + red[p][5]) + (red[p][6] + red[p][7]);
        s1  = (red[p][8] + red[p][9]) + (red[p][10] + red[p][11]);
        ss1 = (red[p][12] + red[p][13]) + (red[p][14] + red[p][15]);

        const float mean0 = s0 * (1.0f / HS);
        const float var0  = fmaf(-mean0, mean0, ss0 * (1.0f / HS));
        const float rstd0 = rsqrtf(var0 + 1e-5f);
        const float mean1 = s1 * (1.0f / HS);
        const float var1  = fmaf(-mean1, mean1, ss1 * (1.0f / HS));
        const float rstd1 = rsqrtf(var1 + 1e-5f);

        float o0x, o0y, o0z, o0w, o1x, o1y, o1z, o1w;
        {
            float ew, eb;
            ew = fmaf(a0.x, w0.x, fmaf(a0.y, w1.x, fmaf(a0.z, w2.x, a0.w * w3.x)));
            eb = fmaf(a0.x, b0.x, fmaf(a0.y, b1.x, fmaf(a0.z, b2.x, a0.w * b3.x)));
            o0x = fmaf((x0.x - mean0) * rstd0, ew, eb);
            ew = fmaf(a0.x, w0.y, fmaf(a0.y, w1.y, fmaf(a0.z, w2.y, a0.w * w3.y)));
            eb = fmaf(a0.x, b0.y, fmaf(a0.y, b1.y, fmaf(a0.z, b2.y, a0.w * b3.y)));
            o0y = fmaf((x0.y - mean0) * rstd0, ew, eb);
            ew = fmaf(a0.x, w0.z, fmaf(a0.y, w1.z, fmaf(a0.z, w2.z, a0.w * w3.z)));
            eb = fmaf(a0.x, b0.z, fmaf(a0.y, b1.z, fmaf(a0.z, b2.z, a0.w * b3.z)));
            o0z = fmaf((x0.z - mean0) * rstd0, ew, eb);
            ew = fmaf(a0.x, w0.w, fmaf(a0.y, w1.w, fmaf(a0.z, w2.w, a0.w * w3.w)));
            eb = fmaf(a0.x, b0.w, fmaf(a0.y, b1.w, fmaf(a0.z, b2.w, a0.w * b3.w)));
            o0w = fmaf((x0.w - mean0) * rstd0, ew, eb);

            ew = fmaf(a1.x, w0.x, fmaf(a1.y, w1.x, fmaf(a1.z, w2.x, a1.w * w3.x)));
            eb = fmaf(a1.x, b0.x, fmaf(a1.y, b1.x, fmaf(a1.z, b2.x, a1.w * b3.x)));
            o1x = fmaf((x1.x - mean1) * rstd1, ew, eb);
            ew = fmaf(a1.x, w0.y, fmaf(a1.y, w1.y, fmaf(a1.z, w2.y, a1.w * w3.y)));
            eb = fmaf(a1.x, b0.y, fmaf(a1.y, b1.y, fmaf(a1.z, b2.y, a1.w * b3.y)));
            o1y = fmaf((x1.y - mean1) * rstd1, ew, eb);
            ew = fmaf(a1.x, w0.z, fmaf(a1.y, w1.z, fmaf(a1.z, w2.z, a1.w * w3.z)));
            eb = fmaf(a1.x, b0.z, fmaf(a1.y, b1.z, fmaf(a1.z, b2.z, a1.w * b3.z)));
            o1z = fmaf((x1.z - mean1) * rstd1, ew, eb);
            ew = fmaf(a1.x, w0.w, fmaf(a1.y, w1.w, fmaf(a1.z, w2.w, a1.w * w3.w)));
            eb = fmaf(a1.x, b0.w, fmaf(a1.y, b1.w, fmaf(a1.z, b2.w, a1.w * b3.w)));
            o1w = fmaf((x1.w - mean1) * rstd1, ew, eb);
        }

        // Non-temporal: don't let the output stream evict x from Infinity Cache.
        st4_nt(out + base0, o0x, o0y, o0z, o0w);
        st4_nt(out + base1, o1x, o1y, o1z, o1w);
    }
}

extern "C" void kernel_launch(void* const* d_in, const int* in_sizes, int n_in,
                              void* d_out, int out_size, void* d_ws, size_t ws_size,
                              hipStream_t stream) {
    const float* x     = (const float*)d_in[0];
    const float* alpha = (const float*)d_in[1];
    const float* W     = (const float*)d_in[2];
    const float* Bias  = (const float*)d_in[3];
    float* out = (float*)d_out;

    const int nrows = in_sizes[0] / HS;  // 4*8192 = 32768

    // Persistent grid: 2048 blocks = 256 CUs x 8 blocks/CU; each block does 8
    // iterations of 2 rows.
    const int grid = 2048;
    lns_kernel<<<grid, 256, 0, stream>>>(x, alpha, W, Bias, out, nrows);
}

// Round 5
// 46.585 us; speedup vs baseline: 1.0548x; 1.0151x over previous
//
#include <hip/hip_runtime.h>

// LayerNormSubspace: out[b,s,h] = xhat[b,s,h] * (alpha[b,s,:] @ W)[h] + (alpha[b,s,:] @ b)[h]
// x: [4,8192,1024] f32, alpha: [4,8192,4] f32, W: [4,1024] f32, b: [4,1024] f32
// 32768 rows of HS=1024.
//
// R4 -> R5: fix compile — update_dpp's dpp_ctrl must be an immediate, so pass
// it as a template parameter. Theory unchanged: __shfl_down was serializing on
// the DS pipe (~37us of ds_swizzle at 512 wave-iters/CU); DPP adds run on the
// VALU pipe instead. DS ops per 2-row wave-iter: ~30 -> ~5.

constexpr int HS = 1024;

typedef float vfloat4 __attribute__((ext_vector_type(4)));

__device__ __forceinline__ float4 ld4(const float* p) {
    return *reinterpret_cast<const float4*>(p);
}

__device__ __forceinline__ void st4_nt(float* p, float a, float b, float c, float d) {
    vfloat4 v = {a, b, c, d};
    __builtin_nontemporal_store(v, reinterpret_cast<vfloat4*>(p));
}

// x += dpp_permute(x, CTRL), 0-fill for invalid source lanes (bound_ctrl=true)
template <int CTRL>
__device__ __forceinline__ float dpp_add(float x) {
    int y = __builtin_amdgcn_update_dpp(0, __float_as_int(x), CTRL, 0xf, 0xf, true);
    return x + __int_as_float(y);
}

// Full 64-lane sum; valid result lives in lane 63 (other lanes hold partials).
__device__ __forceinline__ float wave_sum_to_lane63(float x) {
    x = dpp_add<0x111>(x);  // row_shr:1
    x = dpp_add<0x112>(x);  // row_shr:2
    x = dpp_add<0x114>(x);  // row_shr:4
    x = dpp_add<0x118>(x);  // row_shr:8  -> lane15 of each row-of-16 has row sum
    x = dpp_add<0x142>(x);  // row_bcast15 -> lane31 += lane15, lane63 += lane47
    x = dpp_add<0x143>(x);  // row_bcast31 -> lane63 += lane31 => full sum in lane 63
    return x;
}

__global__ __launch_bounds__(256, 8) void lns_kernel(
    const float* __restrict__ x,
    const float* __restrict__ alpha,
    const float* __restrict__ W,
    const float* __restrict__ Bias,
    float* __restrict__ out,
    int nrows)
{
    const int t = threadIdx.x;
    const int h4 = t * 4;  // this thread's 4-element column within the row

    // Row-invariant: hoist W and b (4 anchors x 4 elems each) into registers once. 32 VGPRs.
    const float4 w0 = ld4(W + 0 * HS + h4);
    const float4 w1 = ld4(W + 1 * HS + h4);
    const float4 w2 = ld4(W + 2 * HS + h4);
    const float4 w3 = ld4(W + 3 * HS + h4);
    const float4 b0 = ld4(Bias + 0 * HS + h4);
    const float4 b1 = ld4(Bias + 1 * HS + h4);
    const float4 b2 = ld4(Bias + 2 * HS + h4);
    const float4 b3 = ld4(Bias + 3 * HS + h4);

    // red[parity][wave] = {s0, ss0, s1, ss1}
    __shared__ vfloat4 red[2][4];

    const int wv = t >> 6;
    int iter = 0;

    for (int row = blockIdx.x * 2; row < nrows; row += gridDim.x * 2, ++iter) {
        const size_t base0 = (size_t)row * HS + h4;
        const size_t base1 = base0 + HS;

        const float4 x0 = ld4(x + base0);
        const float4 x1 = ld4(x + base1);
        const float4 a0 = ld4(alpha + (size_t)row * 4);
        const float4 a1 = ld4(alpha + (size_t)row * 4 + 4);

        float s0  = (x0.x + x0.y) + (x0.z + x0.w);
        float ss0 = fmaf(x0.x, x0.x, fmaf(x0.y, x0.y, fmaf(x0.z, x0.z, x0.w * x0.w)));
        float s1  = (x1.x + x1.y) + (x1.z + x1.w);
        float ss1 = fmaf(x1.x, x1.x, fmaf(x1.y, x1.y, fmaf(x1.z, x1.z, x1.w * x1.w)));

        // VALU-pipe wave reduce (DPP); full sums land in lane 63.
        s0  = wave_sum_to_lane63(s0);
        ss0 = wave_sum_to_lane63(ss0);
        s1  = wave_sum_to_lane63(s1);
        ss1 = wave_sum_to_lane63(ss1);

        const int p = iter & 1;
        if ((t & 63) == 63) {
            vfloat4 v = {s0, ss0, s1, ss1};
            red[p][wv] = v;
        }
        __syncthreads();  // single barrier per 2 rows (parity buffer protects reuse)

        const vfloat4 r0 = red[p][0];
        const vfloat4 r1 = red[p][1];
        const vfloat4 r2 = red[p][2];
        const vfloat4 r3 = red[p][3];
        s0  = (r0.x + r1.x) + (r2.x + r3.x);
        ss0 = (r0.y + r1.y) + (r2.y + r3.y);
        s1  = (r0.z + r1.z) + (r2.z + r3.z);
        ss1 = (r0.w + r1.w) + (r2.w + r3.w);

        const float mean0 = s0 * (1.0f / HS);
        const float var0  = fmaf(-mean0, mean0, ss0 * (1.0f / HS));
        const float rstd0 = rsqrtf(var0 + 1e-5f);
        const float mean1 = s1 * (1.0f / HS);
        const float var1  = fmaf(-mean1, mean1, ss1 * (1.0f / HS));
        const float rstd1 = rsqrtf(var1 + 1e-5f);

        float o0x, o0y, o0z, o0w, o1x, o1y, o1z, o1w;
        {
            float ew, eb;
            ew = fmaf(a0.x, w0.x, fmaf(a0.y, w1.x, fmaf(a0.z, w2.x, a0.w * w3.x)));
            eb = fmaf(a0.x, b0.x, fmaf(a0.y, b1.x, fmaf(a0.z, b2.x, a0.w * b3.x)));
            o0x = fmaf((x0.x - mean0) * rstd0, ew, eb);
            ew = fmaf(a0.x, w0.y, fmaf(a0.y, w1.y, fmaf(a0.z, w2.y, a0.w * w3.y)));
            eb = fmaf(a0.x, b0.y, fmaf(a0.y, b1.y, fmaf(a0.z, b2.y, a0.w * b3.y)));
            o0y = fmaf((x0.y - mean0) * rstd0, ew, eb);
            ew = fmaf(a0.x, w0.z, fmaf(a0.y, w1.z, fmaf(a0.z, w2.z, a0.w * w3.z)));
            eb = fmaf(a0.x, b0.z, fmaf(a0.y, b1.z, fmaf(a0.z, b2.z, a0.w * b3.z)));
            o0z = fmaf((x0.z - mean0) * rstd0, ew, eb);
            ew = fmaf(a0.x, w0.w, fmaf(a0.y, w1.w, fmaf(a0.z, w2.w, a0.w * w3.w)));
            eb = fmaf(a0.x, b0.w, fmaf(a0.y, b1.w, fmaf(a0.z, b2.w, a0.w * b3.w)));
            o0w = fmaf((x0.w - mean0) * rstd0, ew, eb);

            ew = fmaf(a1.x, w0.x, fmaf(a1.y, w1.x, fmaf(a1.z, w2.x, a1.w * w3.x)));
            eb = fmaf(a1.x, b0.x, fmaf(a1.y, b1.x, fmaf(a1.z, b2.x, a1.w * b3.x)));
            o1x = fmaf((x1.x - mean1) * rstd1, ew, eb);
            ew = fmaf(a1.x, w0.y, fmaf(a1.y, w1.y, fmaf(a1.z, w2.y, a1.w * w3.y)));
            eb = fmaf(a1.x, b0.y, fmaf(a1.y, b1.y, fmaf(a1.z, b2.y, a1.w * b3.y)));
            o1y = fmaf((x1.y - mean1) * rstd1, ew, eb);
            ew = fmaf(a1.x, w0.z, fmaf(a1.y, w1.z, fmaf(a1.z, w2.z, a1.w * w3.z)));
            eb = fmaf(a1.x, b0.z, fmaf(a1.y, b1.z, fmaf(a1.z, b2.z, a1.w * b3.z)));
            o1z = fmaf((x1.z - mean1) * rstd1, ew, eb);
            ew = fmaf(a1.x, w0.w, fmaf(a1.y, w1.w, fmaf(a1.z, w2.w, a1.w * w3.w)));
            eb = fmaf(a1.x, b0.w, fmaf(a1.y, b1.w, fmaf(a1.z, b2.w, a1.w * b3.w)));
            o1w = fmaf((x1.w - mean1) * rstd1, ew, eb);
        }

        // Non-temporal: don't let the output stream evict x from Infinity Cache.
        st4_nt(out + base0, o0x, o0y, o0z, o0w);
        st4_nt(out + base1, o1x, o1y, o1z, o1w);
    }
}

extern "C" void kernel_launch(void* const* d_in, const int* in_sizes, int n_in,
                              void* d_out, int out_size, void* d_ws, size_t ws_size,
                              hipStream_t stream) {
    const float* x     = (const float*)d_in[0];
    const float* alpha = (const float*)d_in[1];
    const float* W     = (const float*)d_in[2];
    const float* Bias  = (const float*)d_in[3];
    float* out = (float*)d_out;

    const int nrows = in_sizes[0] / HS;  // 4*8192 = 32768

    // Persistent grid: 2048 blocks = 256 CUs x 8 blocks/CU; each block does 8
    // iterations of 2 rows.
    const int grid = 2048;
    lns_kernel<<<grid, 256, 0, stream>>>(x, alpha, W, Bias, out, nrows);
}

// Round 6
// 46.228 us; speedup vs baseline: 1.0629x; 1.0077x over previous
//
#include <hip/hip_runtime.h>

// LayerNormSubspace: out[b,s,h] = xhat[b,s,h] * (alpha[b,s,:] @ W)[h] + (alpha[b,s,:] @ b)[h]
// x: [4,8192,1024] f32, alpha: [4,8192,4] f32, W: [4,1024] f32, b: [4,1024] f32
// 32768 rows of HS=1024. Compulsory traffic 256.5 MiB -> 42.7us @ 6.29 TB/s.
//
// R5 -> R6: software pipelining. R5 was at 89% of copy roofline; VALU 21%,
// DS near-zero, so the residual is load-issue gaps: loads for iter k+1 sat
// behind the backedge while reduce/barrier/epilogue ran. Now: 4 rows per
// iteration, and iteration k issues iteration k+1's x/alpha loads BEFORE the
// reduce, so ~a full iteration of compute covers their latency. One barrier
// per 4 rows. ~100 VGPR -> 16 waves/CU (launch_bounds(256,4), grid 1024);
// 64 KB/CU of loads in flight >> 9 KB latency-BW product.

constexpr int HS  = 1024;
constexpr int BPI = 4;  // rows per block-iteration

typedef float vfloat4 __attribute__((ext_vector_type(4)));

__device__ __forceinline__ float4 ld4(const float* p) {
    return *reinterpret_cast<const float4*>(p);
}

__device__ __forceinline__ void st4_nt(float* p, float a, float b, float c, float d) {
    vfloat4 v = {a, b, c, d};
    __builtin_nontemporal_store(v, reinterpret_cast<vfloat4*>(p));
}

// x += dpp_permute(x, CTRL), 0-fill for invalid source lanes (bound_ctrl=true)
template <int CTRL>
__device__ __forceinline__ float dpp_add(float x) {
    int y = __builtin_amdgcn_update_dpp(0, __float_as_int(x), CTRL, 0xf, 0xf, true);
    return x + __int_as_float(y);
}

// Full 64-lane sum; valid result lives in lane 63.
__device__ __forceinline__ float wave_sum_to_lane63(float x) {
    x = dpp_add<0x111>(x);  // row_shr:1
    x = dpp_add<0x112>(x);  // row_shr:2
    x = dpp_add<0x114>(x);  // row_shr:4
    x = dpp_add<0x118>(x);  // row_shr:8
    x = dpp_add<0x142>(x);  // row_bcast15
    x = dpp_add<0x143>(x);  // row_bcast31 -> full sum in lane 63
    return x;
}

#define SUMS(xv, s, ss)                                                        \
    float s  = (xv.x + xv.y) + (xv.z + xv.w);                                  \
    float ss = fmaf(xv.x, xv.x, fmaf(xv.y, xv.y, fmaf(xv.z, xv.z, xv.w * xv.w)));

#define EMIT(xv, av, mean, rstd, dst) do {                                     \
    float ew, eb, o0, o1, o2, o3;                                              \
    ew = fmaf(av.x, w0.x, fmaf(av.y, w1.x, fmaf(av.z, w2.x, av.w * w3.x)));    \
    eb = fmaf(av.x, b0.x, fmaf(av.y, b1.x, fmaf(av.z, b2.x, av.w * b3.x)));    \
    o0 = fmaf((xv.x - mean) * rstd, ew, eb);                                   \
    ew = fmaf(av.x, w0.y, fmaf(av.y, w1.y, fmaf(av.z, w2.y, av.w * w3.y)));    \
    eb = fmaf(av.x, b0.y, fmaf(av.y, b1.y, fmaf(av.z, b2.y, av.w * b3.y)));    \
    o1 = fmaf((xv.y - mean) * rstd, ew, eb);                                   \
    ew = fmaf(av.x, w0.z, fmaf(av.y, w1.z, fmaf(av.z, w2.z, av.w * w3.z)));    \
    eb = fmaf(av.x, b0.z, fmaf(av.y, b1.z, fmaf(av.z, b2.z, av.w * b3.z)));    \
    o2 = fmaf((xv.z - mean) * rstd, ew, eb);                                   \
    ew = fmaf(av.x, w0.w, fmaf(av.y, w1.w, fmaf(av.z, w2.w, av.w * w3.w)));    \
    eb = fmaf(av.x, b0.w, fmaf(av.y, b1.w, fmaf(av.z, b2.w, av.w * b3.w)));    \
    o3 = fmaf((xv.w - mean) * rstd, ew, eb);                                   \
    st4_nt(dst, o0, o1, o2, o3);                                               \
} while (0)

__global__ __launch_bounds__(256, 4) void lns_kernel(
    const float* __restrict__ x,
    const float* __restrict__ alpha,
    const float* __restrict__ W,
    const float* __restrict__ Bias,
    float* __restrict__ out,
    int nrows)
{
    const int t  = threadIdx.x;
    const int h4 = t * 4;

    // Row-invariant W/b in registers (32 VGPRs).
    const float4 w0 = ld4(W + 0 * HS + h4);
    const float4 w1 = ld4(W + 1 * HS + h4);
    const float4 w2 = ld4(W + 2 * HS + h4);
    const float4 w3 = ld4(W + 3 * HS + h4);
    const float4 b0 = ld4(Bias + 0 * HS + h4);
    const float4 b1 = ld4(Bias + 1 * HS + h4);
    const float4 b2 = ld4(Bias + 2 * HS + h4);
    const float4 b3 = ld4(Bias + 3 * HS + h4);

    // red[parity][wave][j]: j=0 -> {s0,ss0,s1,ss1}, j=1 -> {s2,ss2,s3,ss3}
    __shared__ vfloat4 red[2][4][2];

    const int wv     = t >> 6;
    const int stride = gridDim.x * BPI;
    const int iters  = nrows / stride;  // exact: 32768 / 4096 = 8
    int row          = blockIdx.x * BPI;

    // Prologue: load iteration 0.
    size_t base = (size_t)row * HS + h4;
    float4 xc0 = ld4(x + base);
    float4 xc1 = ld4(x + base + HS);
    float4 xc2 = ld4(x + base + 2 * HS);
    float4 xc3 = ld4(x + base + 3 * HS);
    const float* ap = alpha + (size_t)row * 4;
    float4 aA = ld4(ap);
    float4 aB = ld4(ap + 4);
    float4 aC = ld4(ap + 8);
    float4 aD = ld4(ap + 12);

    for (int it = 0; it < iters; ++it, row += stride) {
        // Issue NEXT iteration's loads first: a full iteration of compute
        // (reduce + barrier + epilogue) covers their latency.
        float4 xn0, xn1, xn2, xn3, nA, nB, nC, nD;
        const bool more = (it + 1 < iters);
        if (more) {
            const size_t nb = (size_t)(row + stride) * HS + h4;
            xn0 = ld4(x + nb);
            xn1 = ld4(x + nb + HS);
            xn2 = ld4(x + nb + 2 * HS);
            xn3 = ld4(x + nb + 3 * HS);
            const float* np = alpha + (size_t)(row + stride) * 4;
            nA = ld4(np);
            nB = ld4(np + 4);
            nC = ld4(np + 8);
            nD = ld4(np + 12);
        }

        SUMS(xc0, s0, ss0);
        SUMS(xc1, s1, ss1);
        SUMS(xc2, s2, ss2);
        SUMS(xc3, s3, ss3);

        s0  = wave_sum_to_lane63(s0);
        ss0 = wave_sum_to_lane63(ss0);
        s1  = wave_sum_to_lane63(s1);
        ss1 = wave_sum_to_lane63(ss1);
        s2  = wave_sum_to_lane63(s2);
        ss2 = wave_sum_to_lane63(ss2);
        s3  = wave_sum_to_lane63(s3);
        ss3 = wave_sum_to_lane63(ss3);

        const int p = it & 1;
        if ((t & 63) == 63) {
            vfloat4 u = {s0, ss0, s1, ss1};
            vfloat4 v = {s2, ss2, s3, ss3};
            red[p][wv][0] = u;
            red[p][wv][1] = v;
        }
        __syncthreads();  // one barrier per 4 rows; parity buffer protects reuse

        const vfloat4 u0 = red[p][0][0], u1 = red[p][1][0], u2 = red[p][2][0], u3 = red[p][3][0];
        const vfloat4 v0 = red[p][0][1], v1 = red[p][1][1], v2 = red[p][2][1], v3 = red[p][3][1];
        s0  = (u0.x + u1.x) + (u2.x + u3.x);
        ss0 = (u0.y + u1.y) + (u2.y + u3.y);
        s1  = (u0.z + u1.z) + (u2.z + u3.z);
        ss1 = (u0.w + u1.w) + (u2.w + u3.w);
        s2  = (v0.x + v1.x) + (v2.x + v3.x);
        ss2 = (v0.y + v1.y) + (v2.y + v3.y);
        s3  = (v0.z + v1.z) + (v2.z + v3.z);
        ss3 = (v0.w + v1.w) + (v2.w + v3.w);

        const float mean0 = s0 * (1.0f / HS);
        const float rstd0 = rsqrtf(fmaf(-mean0, mean0, ss0 * (1.0f / HS)) + 1e-5f);
        const float mean1 = s1 * (1.0f / HS);
        const float rstd1 = rsqrtf(fmaf(-mean1, mean1, ss1 * (1.0f / HS)) + 1e-5f);
        const float mean2 = s2 * (1.0f / HS);
        const float rstd2 = rsqrtf(fmaf(-mean2, mean2, ss2 * (1.0f / HS)) + 1e-5f);
        const float mean3 = s3 * (1.0f / HS);
        const float rstd3 = rsqrtf(fmaf(-mean3, mean3, ss3 * (1.0f / HS)) + 1e-5f);

        base = (size_t)row * HS + h4;
        EMIT(xc0, aA, mean0, rstd0, out + base);
        EMIT(xc1, aB, mean1, rstd1, out + base + HS);
        EMIT(xc2, aC, mean2, rstd2, out + base + 2 * HS);
        EMIT(xc3, aD, mean3, rstd3, out + base + 3 * HS);

        xc0 = xn0; xc1 = xn1; xc2 = xn2; xc3 = xn3;
        aA = nA; aB = nB; aC = nC; aD = nD;
    }
}

extern "C" void kernel_launch(void* const* d_in, const int* in_sizes, int n_in,
                              void* d_out, int out_size, void* d_ws, size_t ws_size,
                              hipStream_t stream) {
    const float* x     = (const float*)d_in[0];
    const float* alpha = (const float*)d_in[1];
    const float* W     = (const float*)d_in[2];
    const float* Bias  = (const float*)d_in[3];
    float* out = (float*)d_out;

    const int nrows = in_sizes[0] / HS;  // 32768

    // 1024 blocks = 256 CUs x 4 blocks/CU (16 waves/CU at ~100 VGPR);
    // each block runs 8 iterations of 4 rows. 32768 = 1024*4*8 exactly.
    const int grid = 1024;
    lns_kernel<<<grid, 256, 0, stream>>>(x, alpha, W, Bias, out, nrows);
}